// Round 19
// baseline (244.118 us; speedup 1.0000x reference)
//
#include <hip/hip_runtime.h>
#include <hip/hip_cooperative_groups.h>

namespace cg = cooperative_groups;

// ---------------------------------------------------------------------------
// y = x @ Q^T where Q = H_0 H_1 ... H_{N-1}, H_n = I - 2 v_n v_n^T/(v_n.v_n+eps)
// S=256, N=258, B=65536.
//
// TWO launches:
//  hh_fused (cooperative, 512 blocks x 64 thr):
//    Phase A: 8 chunk cascades Q_c = H_{33c}..H_{33c+32} (R13-verbatim fused-
//             norm 33-step chains) -> Qc, QcT.
//    grid.sync() ; L1: 4 products (R12-proven hi/lo-split MFMA merge) -> P,PT
//    grid.sync() ; L2: 2 products -> R,RT
//    grid.sync() ; L3: 1 product -> bf16 Qb
//    (replaces 3 kernel launches + drain gaps, ~25us of the R13 budget,
//     with 3 grid syncs; merge compute is ~2us/level)
//  hh_gemm: y = x @ Qb^T, bf16 MFMA, BM=128 BN=256 BK=32 (proven).
//
// d_ws: Qb (128KB). Qc/QcT/P/PT/R/RT (7MB) in d_out scratch (dead before
// hh_gemm overwrites d_out).
// ---------------------------------------------------------------------------

#define GLOAD_LDS16(g, l)                                                      \
  __builtin_amdgcn_global_load_lds(                                            \
      (const __attribute__((address_space(1))) void*)(g),                      \
      (__attribute__((address_space(3))) void*)(l), 16, 0, 0)

typedef __attribute__((ext_vector_type(8))) short bf16x8;
typedef __attribute__((ext_vector_type(4))) float f32x4;

__device__ __forceinline__ unsigned short f2bf_rne(float f) {
  unsigned u = __builtin_bit_cast(unsigned, f);
  return (unsigned short)((u + 0x7fffu + ((u >> 16) & 1u)) >> 16);
}

struct bfpair { short hi, lo; };

// split fp32 -> hi(bf16) + lo(bf16), x ~= hi + lo, |err| ~ 2^-16 |x|
__device__ __forceinline__ bfpair bf_split(float x) {
  unsigned short hu = f2bf_rne(x);
  float hf = __builtin_bit_cast(float, (unsigned)hu << 16);
  bfpair r;
  r.hi = (short)hu;
  r.lo = (short)f2bf_rne(x - hf);
  return r;
}

// DPP-shuffled add: v + dpp(v). CTRL: 0xB1=quad xor1, 0x4E=quad xor2,
// 0x124=row_ror:4, 0x128=row_ror:8. Pure VALU latency, no LDS.
template <int CTRL>
__device__ __forceinline__ float dpp_add(float v) {
  int t = __builtin_amdgcn_update_dpp(0, __builtin_bit_cast(int, v), CTRL, 0xF,
                                      0xF, true);
  return v + __builtin_bit_cast(float, t);
}

// full 16-lane-group sum (all lanes get the sum)
__device__ __forceinline__ float dpp_sum16(float p) {
  p = dpp_add<0xB1>(p);
  p = dpp_add<0x4E>(p);
  p = dpp_add<0x124>(p);
  p = dpp_add<0x128>(p);
  return p;
}

// ---------------- R12-proven wave-level split-MFMA merge tile ---------------
// One wave computes a 32x32 tile of C = A * B using A rows and B^T rows
// (all f32x4 loads along k). 3-term bf16 hi/lo MFMA, fp32 accumulate.
// outb != nullptr: write bf16 only; else write C and C^T.
__device__ __forceinline__ void merge_tile(const float* __restrict__ A,
                                           const float* __restrict__ BT,
                                           float* __restrict__ C,
                                           float* __restrict__ CT,
                                           unsigned short* __restrict__ outb,
                                           int t, int lane) {
  const int ti = (t >> 3) * 32, tj = (t & 7) * 32;
  const int fr = lane & 15, fg = lane >> 4;

  f32x4 acc[2][2];
#pragma unroll
  for (int m = 0; m < 2; ++m)
#pragma unroll
    for (int n = 0; n < 2; ++n) acc[m][n] = (f32x4){0.f, 0.f, 0.f, 0.f};

  for (int kt = 0; kt < 8; ++kt) {
    const int k0 = kt * 32 + fg * 8;
    bf16x8 ahi[2], alo[2], bhi[2], blo[2];
#pragma unroll
    for (int m = 0; m < 2; ++m) {
      const float* ap = A + (long)(ti + m * 16 + fr) * 256 + k0;
      f32x4 x0 = *(const f32x4*)ap;
      f32x4 x1 = *(const f32x4*)(ap + 4);
#pragma unroll
      for (int e = 0; e < 4; ++e) {
        bfpair p0 = bf_split(x0[e]);
        bfpair p1 = bf_split(x1[e]);
        ahi[m][e] = p0.hi; alo[m][e] = p0.lo;
        ahi[m][4 + e] = p1.hi; alo[m][4 + e] = p1.lo;
      }
    }
#pragma unroll
    for (int n = 0; n < 2; ++n) {
      const float* bp = BT + (long)(tj + n * 16 + fr) * 256 + k0;
      f32x4 x0 = *(const f32x4*)bp;
      f32x4 x1 = *(const f32x4*)(bp + 4);
#pragma unroll
      for (int e = 0; e < 4; ++e) {
        bfpair p0 = bf_split(x0[e]);
        bfpair p1 = bf_split(x1[e]);
        bhi[n][e] = p0.hi; blo[n][e] = p0.lo;
        bhi[n][4 + e] = p1.hi; blo[n][4 + e] = p1.lo;
      }
    }
#pragma unroll
    for (int m = 0; m < 2; ++m)
#pragma unroll
      for (int n = 0; n < 2; ++n) {
        acc[m][n] = __builtin_amdgcn_mfma_f32_16x16x32_bf16(ahi[m], bhi[n],
                                                            acc[m][n], 0, 0, 0);
        acc[m][n] = __builtin_amdgcn_mfma_f32_16x16x32_bf16(ahi[m], blo[n],
                                                            acc[m][n], 0, 0, 0);
        acc[m][n] = __builtin_amdgcn_mfma_f32_16x16x32_bf16(alo[m], bhi[n],
                                                            acc[m][n], 0, 0, 0);
      }
  }

  // C/D layout: col = lane&15, row = (lane>>4)*4 + reg
#pragma unroll
  for (int m = 0; m < 2; ++m)
#pragma unroll
    for (int n = 0; n < 2; ++n)
#pragma unroll
      for (int rr = 0; rr < 4; ++rr) {
        const int grow = ti + m * 16 + fg * 4 + rr;
        const int gcol = tj + n * 16 + fr;
        const float val = acc[m][n][rr];
        if (outb) {
          outb[grow * 256 + gcol] = f2bf_rne(val);
        } else {
          C[grow * 256 + gcol] = val;
          CT[gcol * 256 + grow] = val;
        }
      }
}

// ---------------- Fused cooperative kernel ----------------------------------
__launch_bounds__(64, 1)
__global__ void hh_fused(const float* __restrict__ vecs,
                         float* __restrict__ Qc, float* __restrict__ QcT,
                         float* __restrict__ P, float* __restrict__ PT,
                         float* __restrict__ R, float* __restrict__ RT,
                         unsigned short* __restrict__ Qb) {
  cg::grid_group grid = cg::this_grid();
  const int b = blockIdx.x;   // 0..511
  const int l = threadIdx.x;  // 0..63

  // ======== Phase A: chunk cascades (R13-verbatim, + QcT store) ============
  {
    const int chunk = b >> 6;  // 0..7
    const int rg = b & 63;     // 0..63
    const int r = l >> 4;      // lane group 0..3
    const int cl = l & 15;     // lane in group
    const int row = rg * 4 + r;
    const int col0 = cl * 16;
    const int brow = chunk * 33;

    __shared__ float cs[36];

    // prologue: c_n for n = 0..35 (n>=33 or global row >=258 -> 0)
    for (int n = r; n < 36; n += 4) {
      const int gr = brow + n;
      const int grc = gr > 257 ? 257 : gr;
      const float4* vp = (const float4*)(vecs + (long)grc * 256 + col0);
      float s = 0.f;
#pragma unroll
      for (int i = 0; i < 4; ++i) {
        float4 t = vp[i];
        s += t.x * t.x + t.y * t.y + t.z * t.z + t.w * t.w;
      }
      s = dpp_sum16(s);
      if (cl == 0) cs[n] = (n < 33 && gr < 258) ? 2.0f / (s + 1e-16f) : 0.f;
    }
    __syncthreads();

    float q[16];
#pragma unroll
    for (int i = 0; i < 16; ++i) q[i] = (col0 + i == row) ? 1.f : 0.f;

    auto load16 = [&](float(&d)[16], int n) {
      const int gr = brow + n;
      const int grc = gr > 257 ? 257 : gr;  // clamped; c=0 pad -> no-op step
      const float4* v = (const float4*)(vecs + (long)grc * 256 + col0);
#pragma unroll
      for (int i = 0; i < 4; ++i) {
        float4 t = v[i];
        d[4 * i] = t.x; d[4 * i + 1] = t.y;
        d[4 * i + 2] = t.z; d[4 * i + 3] = t.w;
      }
    };

    auto step = [&](const float(&a)[16], float cc) {
      float p0 = 0.f, p1 = 0.f, p2 = 0.f, p3 = 0.f;
#pragma unroll
      for (int e = 0; e < 4; ++e) {
        p0 = fmaf(q[e], a[e], p0);
        p1 = fmaf(q[4 + e], a[4 + e], p1);
        p2 = fmaf(q[8 + e], a[8 + e], p2);
        p3 = fmaf(q[12 + e], a[12 + e], p3);
      }
      const float p = dpp_sum16((p0 + p1) + (p2 + p3));
      const float s = cc * p;
#pragma unroll
      for (int k = 0; k < 16; ++k) q[k] = fmaf(-s, a[k], q[k]);
    };

    float A0[16], A1[16];
    load16(A0, 0);
    load16(A1, 1);
    float c0 = cs[0], c1 = cs[1];
    for (int n = 0; n < 32; n += 2) {
      const float cn0 = cs[n + 2], cn1 = cs[n + 3];
      step(A0, c0);
      load16(A0, n + 2);
      step(A1, c1);
      load16(A1, n + 3);
      c0 = cn0; c1 = cn1;
    }
    step(A0, c0);  // step 32

    float4* out = (float4*)(Qc + (long)chunk * 65536 + row * 256 + col0);
#pragma unroll
    for (int i = 0; i < 4; ++i)
      out[i] = make_float4(q[4 * i], q[4 * i + 1], q[4 * i + 2], q[4 * i + 3]);
    float* outT = QcT + (long)chunk * 65536 + row;
#pragma unroll
    for (int i = 0; i < 16; ++i) outT[(col0 + i) * 256] = q[i];
  }

  grid.sync();

  // ======== L1: P_p = Qc[2p] * Qc[2p+1], p = 0..3 ==========================
  if (b < 256) {
    const int p = b >> 6, t = b & 63;
    merge_tile(Qc + (long)p * 2 * 65536, QcT + (long)p * 2 * 65536 + 65536,
               P + (long)p * 65536, PT + (long)p * 65536, nullptr, t, l);
  }

  grid.sync();

  // ======== L2: R_p = P[2p] * P[2p+1], p = 0..1 ============================
  if (b < 128) {
    const int p = b >> 6, t = b & 63;
    merge_tile(P + (long)p * 2 * 65536, PT + (long)p * 2 * 65536 + 65536,
               R + (long)p * 65536, RT + (long)p * 65536, nullptr, t, l);
  }

  grid.sync();

  // ======== L3: Qb = bf16( R[0] * R[1] ) ===================================
  if (b < 64) {
    merge_tile(R, RT + 65536, nullptr, nullptr, Qb, b, l);
  }
}

// ---------------- Phase 3: GEMM --------------------------------------------
// C[M=65536][256] = A[M][K=256](f32, cvt->bf16) * B[N=256][K=256](bf16, BT)
// Block: BM=128, BN=256, BK=32, 512 thr (8 waves). Wave grid 2x4, 64x64/wave.
// LDS 64KB dbuf; XOR-swizzled staging via pre-swizzled GLOBAL source address.
__launch_bounds__(512)
__global__ void hh_gemm(const float* __restrict__ X,
                        const unsigned short* __restrict__ Qb,
                        float* __restrict__ Y) {
  __shared__ __align__(128) char lds[65536];
  const int tid = threadIdx.x;
  const int lane = tid & 63;
  const int wid = tid >> 6;
  const int wm = wid >> 2;  // 0..1
  const int wn = wid & 3;   // 0..3
  const int fr = lane & 15;
  const int fg = lane >> 4;
  const long bm0 = (long)blockIdx.x * 128;

  auto stage = [&](int buf, int kt) {
#pragma unroll
    for (int r2 = 0; r2 < 2; ++r2) {
      int slot = r2 * 512 + tid;
      int row = slot >> 3, seg = slot & 7;
      int ps = seg ^ (row & 7);
      GLOAD_LDS16(X + (bm0 + row) * 256 + kt * 32 + ps * 4,
                  lds + buf * 16384 + slot * 16);
    }
#pragma unroll
    for (int r2 = 0; r2 < 2; ++r2) {
      int slot = r2 * 512 + tid;
      int row = slot >> 2, seg = slot & 3;
      int ps = seg ^ (row & 3);
      GLOAD_LDS16(Qb + row * 256 + kt * 32 + ps * 8,
                  lds + 32768 + buf * 16384 + slot * 16);
    }
  };

  f32x4 acc[4][4];
#pragma unroll
  for (int m = 0; m < 4; ++m)
#pragma unroll
    for (int n = 0; n < 4; ++n) acc[m][n] = (f32x4){0.f, 0.f, 0.f, 0.f};

  stage(0, 0);
  __syncthreads();

  for (int kt = 0; kt < 8; ++kt) {
    const int cur = kt & 1;
    if (kt < 7) stage(cur ^ 1, kt + 1);

    bf16x8 aF[4], bF[4];
#pragma unroll
    for (int m = 0; m < 4; ++m) {
      int row = wm * 64 + m * 16 + fr;
      int s0 = (2 * fg) ^ (row & 7);
      int s1 = (2 * fg + 1) ^ (row & 7);
      const f32x4 x0 = *(const f32x4*)(lds + cur * 16384 + row * 128 + s0 * 16);
      const f32x4 x1 = *(const f32x4*)(lds + cur * 16384 + row * 128 + s1 * 16);
      bf16x8 t;
      t[0] = (short)f2bf_rne(x0[0]);
      t[1] = (short)f2bf_rne(x0[1]);
      t[2] = (short)f2bf_rne(x0[2]);
      t[3] = (short)f2bf_rne(x0[3]);
      t[4] = (short)f2bf_rne(x1[0]);
      t[5] = (short)f2bf_rne(x1[1]);
      t[6] = (short)f2bf_rne(x1[2]);
      t[7] = (short)f2bf_rne(x1[3]);
      aF[m] = t;
    }
#pragma unroll
    for (int n = 0; n < 4; ++n) {
      int row = wn * 64 + n * 16 + fr;
      int ps = fg ^ (row & 3);
      bF[n] = *(const bf16x8*)(lds + 32768 + cur * 16384 + row * 64 + ps * 16);
    }
#pragma unroll
    for (int m = 0; m < 4; ++m)
#pragma unroll
      for (int n = 0; n < 4; ++n)
        acc[m][n] =
            __builtin_amdgcn_mfma_f32_16x16x32_bf16(aF[m], bF[n], acc[m][n], 0, 0, 0);
    __syncthreads();
  }

#pragma unroll
  for (int m = 0; m < 4; ++m)
#pragma unroll
    for (int n = 0; n < 4; ++n)
#pragma unroll
      for (int r = 0; r < 4; ++r) {
        long grow = bm0 + wm * 64 + m * 16 + fg * 4 + r;
        int gcol = wn * 64 + n * 16 + fr;
        Y[grow * 256 + gcol] = acc[m][n][r];
      }
}

// ---------------------------------------------------------------------------
extern "C" void kernel_launch(void* const* d_in, const int* in_sizes, int n_in,
                              void* d_out, int out_size, void* d_ws, size_t ws_size,
                              hipStream_t stream) {
  const float* x = (const float*)d_in[0];      // [65536][256] f32
  const float* vecs = (const float*)d_in[1];   // [258][256] f32
  float* y = (float*)d_out;                    // [65536][256] f32

  unsigned short* Qb = (unsigned short*)d_ws;  // 256x256 bf16 (128KB)

  // d_out scratch (7MB; dead before hh_gemm overwrites d_out)
  char* ob = (char*)d_out;
  float* Qc = (float*)(ob);                  // 8 x 64KB f32 (2 MB)
  float* QcT = (float*)(ob + 2097152);       // 8 x 64KB f32 (2 MB)
  float* P = (float*)(ob + 4194304);         // 4 x 64KB f32 (1 MB)
  float* PT = (float*)(ob + 5242880);        // 4 x 64KB f32 (1 MB)
  float* R = (float*)(ob + 6291456);         // 2 x 64KB f32 (512 KB)
  float* RT = (float*)(ob + 6815744);        // 2 x 64KB f32 (512 KB)

  void* args[] = {(void*)&vecs, (void*)&Qc, (void*)&QcT, (void*)&P,
                  (void*)&PT,   (void*)&R,  (void*)&RT,  (void*)&Qb};
  hipLaunchCooperativeKernel((void*)hh_fused, dim3(512), dim3(64), args, 0,
                             stream);
  hh_gemm<<<512, 512, 0, stream>>>(x, Qb, y);
}

// Round 20
// 98.214 us; speedup vs baseline: 2.4856x; 2.4856x over previous
//
#include <hip/hip_runtime.h>

// ---------------------------------------------------------------------------
// y = x @ Q^T where Q = H_0 H_1 ... H_{N-1}, H_n = I - 2 v_n v_n^T/(v_n.v_n+eps)
// S=256, N=258, B=65536.
//
// THREE kernels (R19 post-mortem: grid.sync ~ 60us -> cooperative fusion dead;
// edges are ~1-2us (R14); the 3 hh_mm levels were the ~40us whale):
//  hh_qchunk: 8 chunk cascades Q_c = H_{33c}..H_{33c+32} (R13-verbatim chain,
//             HW-passed twice) + NEW epilogue: store Qc^T pre-split as bf16
//             hi/lo (QcTh/QcTl) so the merge needs ZERO split VALU on B.
//  hh_qmerge: ONE kernel replaces the whole merge tree. 16 blocks x 256 thr;
//             block owns 16 rows; chains Cur <- Cur * Qc_i (i=1..7) with the
//             running panel in LDS as bf16 hi/lo (split once per product at
//             write-back). 3-term hi/lo MFMA (R12-verified ~1e-4 rel).
//             Fragment layouts identical to the proven hh_gemm.
//  hh_gemm:   y = x @ Qb^T, bf16 MFMA, BM=128 BN=256 BK=32 (proven, ~10.5us).
//
// d_ws: Qb (128KB). Qc (2MB f32) + QcTh/QcTl (1MB each, bf16) in d_out
// scratch -- every byte written before read each call; hh_gemm overwrites.
// ---------------------------------------------------------------------------

#define GLOAD_LDS16(g, l)                                                      \
  __builtin_amdgcn_global_load_lds(                                            \
      (const __attribute__((address_space(1))) void*)(g),                      \
      (__attribute__((address_space(3))) void*)(l), 16, 0, 0)

typedef __attribute__((ext_vector_type(8))) short bf16x8;
typedef __attribute__((ext_vector_type(4))) float f32x4;

__device__ __forceinline__ unsigned short f2bf_rne(float f) {
  unsigned u = __builtin_bit_cast(unsigned, f);
  return (unsigned short)((u + 0x7fffu + ((u >> 16) & 1u)) >> 16);
}

struct bfpair { unsigned short hi, lo; };

// split fp32 -> hi(bf16) + lo(bf16), x ~= hi + lo, |err| ~ 2^-16 |x|
__device__ __forceinline__ bfpair bf_split(float x) {
  unsigned short hu = f2bf_rne(x);
  float hf = __builtin_bit_cast(float, (unsigned)hu << 16);
  bfpair r;
  r.hi = hu;
  r.lo = f2bf_rne(x - hf);
  return r;
}

// DPP-shuffled add: v + dpp(v). CTRL: 0xB1=quad xor1, 0x4E=quad xor2,
// 0x124=row_ror:4, 0x128=row_ror:8. Pure VALU latency, no LDS.
template <int CTRL>
__device__ __forceinline__ float dpp_add(float v) {
  int t = __builtin_amdgcn_update_dpp(0, __builtin_bit_cast(int, v), CTRL, 0xF,
                                      0xF, true);
  return v + __builtin_bit_cast(float, t);
}

// full 16-lane-group sum (all lanes get the sum)
__device__ __forceinline__ float dpp_sum16(float p) {
  p = dpp_add<0xB1>(p);
  p = dpp_add<0x4E>(p);
  p = dpp_add<0x124>(p);
  p = dpp_add<0x128>(p);
  return p;
}

// ---------------- Phase 1: chunk cascades (R13-verbatim + T-split store) ----
// 512 blocks x 64 threads (1 wave). Block = (chunk=bx>>6, rowgroup=bx&63).
// Lane l: row-in-group r=l>>4 (4 Q-rows/block), col-group cl=l&15.
__launch_bounds__(64, 1)
__global__ void hh_qchunk(const float* __restrict__ vecs,
                          float* __restrict__ Qc,
                          unsigned short* __restrict__ QcTh,
                          unsigned short* __restrict__ QcTl) {
  const int l = threadIdx.x;
  const int chunk = blockIdx.x >> 6;   // 0..7
  const int rg = blockIdx.x & 63;      // 0..63
  const int r = l >> 4;                // lane group 0..3
  const int cl = l & 15;               // lane in group
  const int row = rg * 4 + r;
  const int col0 = cl * 16;
  const int brow = chunk * 33;

  __shared__ float cs[36];

  // prologue: c_n for n = 0..35 (n>=33 or global row >=258 -> 0)
  for (int n = r; n < 36; n += 4) {
    const int gr = brow + n;
    const int grc = gr > 257 ? 257 : gr;
    const float4* vp = (const float4*)(vecs + (long)grc * 256 + col0);
    float s = 0.f;
#pragma unroll
    for (int i = 0; i < 4; ++i) {
      float4 t = vp[i];
      s += t.x * t.x + t.y * t.y + t.z * t.z + t.w * t.w;
    }
    s = dpp_sum16(s);
    if (cl == 0) cs[n] = (n < 33 && gr < 258) ? 2.0f / (s + 1e-16f) : 0.f;
  }
  __syncthreads();

  float q[16];
#pragma unroll
  for (int i = 0; i < 16; ++i) q[i] = (col0 + i == row) ? 1.f : 0.f;

  auto load16 = [&](float(&d)[16], int n) {
    const int gr = brow + n;
    const int grc = gr > 257 ? 257 : gr;  // clamped; c=0 pad -> no-op step
    const float4* v = (const float4*)(vecs + (long)grc * 256 + col0);
#pragma unroll
    for (int i = 0; i < 4; ++i) {
      float4 t = v[i];
      d[4 * i] = t.x; d[4 * i + 1] = t.y;
      d[4 * i + 2] = t.z; d[4 * i + 3] = t.w;
    }
  };

  auto step = [&](const float(&a)[16], float cc) {
    float p0 = 0.f, p1 = 0.f, p2 = 0.f, p3 = 0.f;
#pragma unroll
    for (int e = 0; e < 4; ++e) {
      p0 = fmaf(q[e], a[e], p0);
      p1 = fmaf(q[4 + e], a[4 + e], p1);
      p2 = fmaf(q[8 + e], a[8 + e], p2);
      p3 = fmaf(q[12 + e], a[12 + e], p3);
    }
    const float p = dpp_sum16((p0 + p1) + (p2 + p3));
    const float s = cc * p;
#pragma unroll
    for (int k = 0; k < 16; ++k) q[k] = fmaf(-s, a[k], q[k]);
  };

  float A0[16], A1[16];
  load16(A0, 0);
  load16(A1, 1);
  float c0 = cs[0], c1 = cs[1];
  for (int n = 0; n < 32; n += 2) {
    const float cn0 = cs[n + 2], cn1 = cs[n + 3];
    step(A0, c0);
    load16(A0, n + 2);
    step(A1, c1);
    load16(A1, n + 3);
    c0 = cn0; c1 = cn1;
  }
  step(A0, c0);  // step 32

  // epilogue: Qc (f32 row-major) + QcT pre-split bf16 hi/lo (scatter stores)
  float4* out = (float4*)(Qc + (long)chunk * 65536 + row * 256 + col0);
#pragma unroll
  for (int i = 0; i < 4; ++i)
    out[i] = make_float4(q[4 * i], q[4 * i + 1], q[4 * i + 2], q[4 * i + 3]);
  unsigned short* oth = QcTh + (long)chunk * 65536 + row;
  unsigned short* otl = QcTl + (long)chunk * 65536 + row;
#pragma unroll
  for (int i = 0; i < 16; ++i) {
    bfpair p = bf_split(q[i]);
    oth[(col0 + i) * 256] = p.hi;
    otl[(col0 + i) * 256] = p.lo;
  }
}

// ---------------- Phase 2: chained-panel merge ------------------------------
// 16 blocks x 256 thr (4 waves). Block owns output rows [16b, 16b+16).
// LDS: running panel Cur (16x256) as bf16 hi/lo, pad 264 (2-way banks, free).
// Wave w computes cols [64w, 64w+64) of Cur * Qc_i via 3-term hi/lo MFMA;
// B-frags load DIRECTLY from pre-split QcTh/QcTl (zero split VALU).
__launch_bounds__(256)
__global__ void hh_qmerge(const float* __restrict__ Qc,
                          const unsigned short* __restrict__ QcTh,
                          const unsigned short* __restrict__ QcTl,
                          unsigned short* __restrict__ Qb) {
  __shared__ __align__(16) unsigned short CurHi[16][264];
  __shared__ __align__(16) unsigned short CurLo[16][264];
  const int tid = threadIdx.x;
  const int lane = tid & 63, w = tid >> 6;   // wave 0..3
  const int fr = lane & 15, fg = lane >> 4;  // frag row / k-group
  const int rb = blockIdx.x * 16;            // block's 16 output rows

  // init: Cur = Qc0 rows [rb, rb+16), split to hi/lo
  {
    const int rr = tid >> 4, c0 = (tid & 15) * 16;
    const float* src = Qc + (long)(rb + rr) * 256 + c0;
#pragma unroll
    for (int i = 0; i < 16; ++i) {
      bfpair p = bf_split(src[i]);
      CurHi[rr][c0 + i] = p.hi;
      CurLo[rr][c0 + i] = p.lo;
    }
  }
  __syncthreads();

  for (int prod = 1; prod < 8; ++prod) {
    const unsigned short* BTh = QcTh + (long)prod * 65536;
    const unsigned short* BTl = QcTl + (long)prod * 65536;
    f32x4 acc[4];
#pragma unroll
    for (int n = 0; n < 4; ++n) acc[n] = (f32x4){0.f, 0.f, 0.f, 0.f};

    for (int kt = 0; kt < 8; ++kt) {
      const int k0 = kt * 32 + fg * 8;
      const bf16x8 aHi = *(const bf16x8*)&CurHi[fr][k0];
      const bf16x8 aLo = *(const bf16x8*)&CurLo[fr][k0];
#pragma unroll
      for (int n = 0; n < 4; ++n) {
        const long bcol = w * 64 + n * 16 + fr;
        const bf16x8 bHi = *(const bf16x8*)(BTh + bcol * 256 + k0);
        const bf16x8 bLo = *(const bf16x8*)(BTl + bcol * 256 + k0);
        acc[n] = __builtin_amdgcn_mfma_f32_16x16x32_bf16(aHi, bHi, acc[n], 0, 0, 0);
        acc[n] = __builtin_amdgcn_mfma_f32_16x16x32_bf16(aHi, bLo, acc[n], 0, 0, 0);
        acc[n] = __builtin_amdgcn_mfma_f32_16x16x32_bf16(aLo, bHi, acc[n], 0, 0, 0);
      }
    }
    __syncthreads();  // all waves done reading Cur

    if (prod < 7) {
      // write back: C/D layout col = lane&15, row = fg*4 + reg
#pragma unroll
      for (int n = 0; n < 4; ++n)
#pragma unroll
        for (int rr = 0; rr < 4; ++rr) {
          bfpair p = bf_split(acc[n][rr]);
          CurHi[fg * 4 + rr][w * 64 + n * 16 + fr] = p.hi;
          CurLo[fg * 4 + rr][w * 64 + n * 16 + fr] = p.lo;
        }
      __syncthreads();
    } else {
#pragma unroll
      for (int n = 0; n < 4; ++n)
#pragma unroll
        for (int rr = 0; rr < 4; ++rr)
          Qb[(long)(rb + fg * 4 + rr) * 256 + w * 64 + n * 16 + fr] =
              f2bf_rne(acc[n][rr]);
    }
  }
}

// ---------------- Phase 3: GEMM --------------------------------------------
// C[M=65536][256] = A[M][K=256](f32, cvt->bf16) * B[N=256][K=256](bf16, BT)
// Block: BM=128, BN=256, BK=32, 512 thr (8 waves). Wave grid 2x4, 64x64/wave.
// LDS 64KB dbuf; XOR-swizzled staging via pre-swizzled GLOBAL source address.
__launch_bounds__(512)
__global__ void hh_gemm(const float* __restrict__ X,
                        const unsigned short* __restrict__ Qb,
                        float* __restrict__ Y) {
  __shared__ __align__(128) char lds[65536];
  const int tid = threadIdx.x;
  const int lane = tid & 63;
  const int wid = tid >> 6;
  const int wm = wid >> 2;  // 0..1
  const int wn = wid & 3;   // 0..3
  const int fr = lane & 15;
  const int fg = lane >> 4;
  const long bm0 = (long)blockIdx.x * 128;

  auto stage = [&](int buf, int kt) {
#pragma unroll
    for (int r2 = 0; r2 < 2; ++r2) {
      int slot = r2 * 512 + tid;
      int row = slot >> 3, seg = slot & 7;
      int ps = seg ^ (row & 7);
      GLOAD_LDS16(X + (bm0 + row) * 256 + kt * 32 + ps * 4,
                  lds + buf * 16384 + slot * 16);
    }
#pragma unroll
    for (int r2 = 0; r2 < 2; ++r2) {
      int slot = r2 * 512 + tid;
      int row = slot >> 2, seg = slot & 3;
      int ps = seg ^ (row & 3);
      GLOAD_LDS16(Qb + row * 256 + kt * 32 + ps * 8,
                  lds + 32768 + buf * 16384 + slot * 16);
    }
  };

  f32x4 acc[4][4];
#pragma unroll
  for (int m = 0; m < 4; ++m)
#pragma unroll
    for (int n = 0; n < 4; ++n) acc[m][n] = (f32x4){0.f, 0.f, 0.f, 0.f};

  stage(0, 0);
  __syncthreads();

  for (int kt = 0; kt < 8; ++kt) {
    const int cur = kt & 1;
    if (kt < 7) stage(cur ^ 1, kt + 1);

    bf16x8 aF[4], bF[4];
#pragma unroll
    for (int m = 0; m < 4; ++m) {
      int row = wm * 64 + m * 16 + fr;
      int s0 = (2 * fg) ^ (row & 7);
      int s1 = (2 * fg + 1) ^ (row & 7);
      const f32x4 x0 = *(const f32x4*)(lds + cur * 16384 + row * 128 + s0 * 16);
      const f32x4 x1 = *(const f32x4*)(lds + cur * 16384 + row * 128 + s1 * 16);
      bf16x8 t;
      t[0] = (short)f2bf_rne(x0[0]);
      t[1] = (short)f2bf_rne(x0[1]);
      t[2] = (short)f2bf_rne(x0[2]);
      t[3] = (short)f2bf_rne(x0[3]);
      t[4] = (short)f2bf_rne(x1[0]);
      t[5] = (short)f2bf_rne(x1[1]);
      t[6] = (short)f2bf_rne(x1[2]);
      t[7] = (short)f2bf_rne(x1[3]);
      aF[m] = t;
    }
#pragma unroll
    for (int n = 0; n < 4; ++n) {
      int row = wn * 64 + n * 16 + fr;
      int ps = fg ^ (row & 3);
      bF[n] = *(const bf16x8*)(lds + 32768 + cur * 16384 + row * 64 + ps * 16);
    }
#pragma unroll
    for (int m = 0; m < 4; ++m)
#pragma unroll
      for (int n = 0; n < 4; ++n)
        acc[m][n] =
            __builtin_amdgcn_mfma_f32_16x16x32_bf16(aF[m], bF[n], acc[m][n], 0, 0, 0);
    __syncthreads();
  }

#pragma unroll
  for (int m = 0; m < 4; ++m)
#pragma unroll
    for (int n = 0; n < 4; ++n)
#pragma unroll
      for (int r = 0; r < 4; ++r) {
        long grow = bm0 + wm * 64 + m * 16 + fg * 4 + r;
        int gcol = wn * 64 + n * 16 + fr;
        Y[grow * 256 + gcol] = acc[m][n][r];
      }
}

// ---------------------------------------------------------------------------
extern "C" void kernel_launch(void* const* d_in, const int* in_sizes, int n_in,
                              void* d_out, int out_size, void* d_ws, size_t ws_size,
                              hipStream_t stream) {
  const float* x = (const float*)d_in[0];      // [65536][256] f32
  const float* vecs = (const float*)d_in[1];   // [258][256] f32
  float* y = (float*)d_out;                    // [65536][256] f32

  unsigned short* Qb = (unsigned short*)d_ws;  // 256x256 bf16 (128KB)

  // d_out scratch (4MB; every byte written by hh_qchunk before any read;
  // dead before hh_gemm overwrites d_out)
  char* ob = (char*)d_out;
  float* Qc = (float*)(ob);                          // 8 x 64K f32  (2 MB)
  unsigned short* QcTh = (unsigned short*)(ob + 2097152);  // 8 x 64K bf16 (1 MB)
  unsigned short* QcTl = (unsigned short*)(ob + 3145728);  // 8 x 64K bf16 (1 MB)

  hh_qchunk<<<512, 64, 0, stream>>>(vecs, Qc, QcTh, QcTl);
  hh_qmerge<<<16, 256, 0, stream>>>(Qc, QcTh, QcTl, Qb);
  hh_gemm<<<512, 512, 0, stream>>>(x, Qb, y);
}

// Round 21
// 98.147 us; speedup vs baseline: 2.4873x; 1.0007x over previous
//
#include <hip/hip_runtime.h>

// ---------------------------------------------------------------------------
// y = x @ Q^T where Q = H_0 H_1 ... H_{N-1}, H_n = I - 2 v_n v_n^T/(v_n.v_n+eps)
// S=256, N=258, B=65536.
//
// THREE kernels (R19 post-mortem: grid.sync ~ 60us -> cooperative fusion dead;
// edges are ~1-2us (R14); the 3 hh_mm levels were the ~40us whale):
//  hh_qchunk: 8 chunk cascades Q_c = H_{33c}..H_{33c+32} (R13-verbatim chain,
//             HW-passed twice) + NEW epilogue: store Qc^T pre-split as bf16
//             hi/lo (QcTh/QcTl) so the merge needs ZERO split VALU on B.
//  hh_qmerge: ONE kernel replaces the whole merge tree. 16 blocks x 256 thr;
//             block owns 16 rows; chains Cur <- Cur * Qc_i (i=1..7) with the
//             running panel in LDS as bf16 hi/lo (split once per product at
//             write-back). 3-term hi/lo MFMA (R12-verified ~1e-4 rel).
//             Fragment layouts identical to the proven hh_gemm.
//  hh_gemm:   y = x @ Qb^T, bf16 MFMA, BM=128 BN=256 BK=32 (proven, ~10.5us).
//
// d_ws: Qb (128KB). Qc (2MB f32) + QcTh/QcTl (1MB each, bf16) in d_out
// scratch -- every byte written before read each call; hh_gemm overwrites.
// ---------------------------------------------------------------------------

#define GLOAD_LDS16(g, l)                                                      \
  __builtin_amdgcn_global_load_lds(                                            \
      (const __attribute__((address_space(1))) void*)(g),                      \
      (__attribute__((address_space(3))) void*)(l), 16, 0, 0)

typedef __attribute__((ext_vector_type(8))) short bf16x8;
typedef __attribute__((ext_vector_type(4))) float f32x4;

__device__ __forceinline__ unsigned short f2bf_rne(float f) {
  unsigned u = __builtin_bit_cast(unsigned, f);
  return (unsigned short)((u + 0x7fffu + ((u >> 16) & 1u)) >> 16);
}

struct bfpair { unsigned short hi, lo; };

// split fp32 -> hi(bf16) + lo(bf16), x ~= hi + lo, |err| ~ 2^-16 |x|
__device__ __forceinline__ bfpair bf_split(float x) {
  unsigned short hu = f2bf_rne(x);
  float hf = __builtin_bit_cast(float, (unsigned)hu << 16);
  bfpair r;
  r.hi = hu;
  r.lo = f2bf_rne(x - hf);
  return r;
}

// DPP-shuffled add: v + dpp(v). CTRL: 0xB1=quad xor1, 0x4E=quad xor2,
// 0x124=row_ror:4, 0x128=row_ror:8. Pure VALU latency, no LDS.
template <int CTRL>
__device__ __forceinline__ float dpp_add(float v) {
  int t = __builtin_amdgcn_update_dpp(0, __builtin_bit_cast(int, v), CTRL, 0xF,
                                      0xF, true);
  return v + __builtin_bit_cast(float, t);
}

// full 16-lane-group sum (all lanes get the sum)
__device__ __forceinline__ float dpp_sum16(float p) {
  p = dpp_add<0xB1>(p);
  p = dpp_add<0x4E>(p);
  p = dpp_add<0x124>(p);
  p = dpp_add<0x128>(p);
  return p;
}

// ---------------- Phase 1: chunk cascades (R13-verbatim + T-split store) ----
// 512 blocks x 64 threads (1 wave). Block = (chunk=bx>>6, rowgroup=bx&63).
// Lane l: row-in-group r=l>>4 (4 Q-rows/block), col-group cl=l&15.
__launch_bounds__(64, 1)
__global__ void hh_qchunk(const float* __restrict__ vecs,
                          float* __restrict__ Qc,
                          unsigned short* __restrict__ QcTh,
                          unsigned short* __restrict__ QcTl) {
  const int l = threadIdx.x;
  const int chunk = blockIdx.x >> 6;   // 0..7
  const int rg = blockIdx.x & 63;      // 0..63
  const int r = l >> 4;                // lane group 0..3
  const int cl = l & 15;               // lane in group
  const int row = rg * 4 + r;
  const int col0 = cl * 16;
  const int brow = chunk * 33;

  __shared__ float cs[36];

  // prologue: c_n for n = 0..35 (n>=33 or global row >=258 -> 0)
  for (int n = r; n < 36; n += 4) {
    const int gr = brow + n;
    const int grc = gr > 257 ? 257 : gr;
    const float4* vp = (const float4*)(vecs + (long)grc * 256 + col0);
    float s = 0.f;
#pragma unroll
    for (int i = 0; i < 4; ++i) {
      float4 t = vp[i];
      s += t.x * t.x + t.y * t.y + t.z * t.z + t.w * t.w;
    }
    s = dpp_sum16(s);
    if (cl == 0) cs[n] = (n < 33 && gr < 258) ? 2.0f / (s + 1e-16f) : 0.f;
  }
  __syncthreads();

  float q[16];
#pragma unroll
  for (int i = 0; i < 16; ++i) q[i] = (col0 + i == row) ? 1.f : 0.f;

  auto load16 = [&](float(&d)[16], int n) {
    const int gr = brow + n;
    const int grc = gr > 257 ? 257 : gr;  // clamped; c=0 pad -> no-op step
    const float4* v = (const float4*)(vecs + (long)grc * 256 + col0);
#pragma unroll
    for (int i = 0; i < 4; ++i) {
      float4 t = v[i];
      d[4 * i] = t.x; d[4 * i + 1] = t.y;
      d[4 * i + 2] = t.z; d[4 * i + 3] = t.w;
    }
  };

  auto step = [&](const float(&a)[16], float cc) {
    float p0 = 0.f, p1 = 0.f, p2 = 0.f, p3 = 0.f;
#pragma unroll
    for (int e = 0; e < 4; ++e) {
      p0 = fmaf(q[e], a[e], p0);
      p1 = fmaf(q[4 + e], a[4 + e], p1);
      p2 = fmaf(q[8 + e], a[8 + e], p2);
      p3 = fmaf(q[12 + e], a[12 + e], p3);
    }
    const float p = dpp_sum16((p0 + p1) + (p2 + p3));
    const float s = cc * p;
#pragma unroll
    for (int k = 0; k < 16; ++k) q[k] = fmaf(-s, a[k], q[k]);
  };

  float A0[16], A1[16];
  load16(A0, 0);
  load16(A1, 1);
  float c0 = cs[0], c1 = cs[1];
  for (int n = 0; n < 32; n += 2) {
    const float cn0 = cs[n + 2], cn1 = cs[n + 3];
    step(A0, c0);
    load16(A0, n + 2);
    step(A1, c1);
    load16(A1, n + 3);
    c0 = cn0; c1 = cn1;
  }
  step(A0, c0);  // step 32

  // epilogue: Qc (f32 row-major) + QcT pre-split bf16 hi/lo (scatter stores)
  float4* out = (float4*)(Qc + (long)chunk * 65536 + row * 256 + col0);
#pragma unroll
  for (int i = 0; i < 4; ++i)
    out[i] = make_float4(q[4 * i], q[4 * i + 1], q[4 * i + 2], q[4 * i + 3]);
  unsigned short* oth = QcTh + (long)chunk * 65536 + row;
  unsigned short* otl = QcTl + (long)chunk * 65536 + row;
#pragma unroll
  for (int i = 0; i < 16; ++i) {
    bfpair p = bf_split(q[i]);
    oth[(col0 + i) * 256] = p.hi;
    otl[(col0 + i) * 256] = p.lo;
  }
}

// ---------------- Phase 2: chained-panel merge ------------------------------
// 16 blocks x 256 thr (4 waves). Block owns output rows [16b, 16b+16).
// LDS: running panel Cur (16x256) as bf16 hi/lo, pad 264 (2-way banks, free).
// Wave w computes cols [64w, 64w+64) of Cur * Qc_i via 3-term hi/lo MFMA;
// B-frags load DIRECTLY from pre-split QcTh/QcTl (zero split VALU).
__launch_bounds__(256)
__global__ void hh_qmerge(const float* __restrict__ Qc,
                          const unsigned short* __restrict__ QcTh,
                          const unsigned short* __restrict__ QcTl,
                          unsigned short* __restrict__ Qb) {
  __shared__ __align__(16) unsigned short CurHi[16][264];
  __shared__ __align__(16) unsigned short CurLo[16][264];
  const int tid = threadIdx.x;
  const int lane = tid & 63, w = tid >> 6;   // wave 0..3
  const int fr = lane & 15, fg = lane >> 4;  // frag row / k-group
  const int rb = blockIdx.x * 16;            // block's 16 output rows

  // init: Cur = Qc0 rows [rb, rb+16), split to hi/lo
  {
    const int rr = tid >> 4, c0 = (tid & 15) * 16;
    const float* src = Qc + (long)(rb + rr) * 256 + c0;
#pragma unroll
    for (int i = 0; i < 16; ++i) {
      bfpair p = bf_split(src[i]);
      CurHi[rr][c0 + i] = p.hi;
      CurLo[rr][c0 + i] = p.lo;
    }
  }
  __syncthreads();

  for (int prod = 1; prod < 8; ++prod) {
    const unsigned short* BTh = QcTh + (long)prod * 65536;
    const unsigned short* BTl = QcTl + (long)prod * 65536;
    f32x4 acc[4];
#pragma unroll
    for (int n = 0; n < 4; ++n) acc[n] = (f32x4){0.f, 0.f, 0.f, 0.f};

    for (int kt = 0; kt < 8; ++kt) {
      const int k0 = kt * 32 + fg * 8;
      const bf16x8 aHi = *(const bf16x8*)&CurHi[fr][k0];
      const bf16x8 aLo = *(const bf16x8*)&CurLo[fr][k0];
#pragma unroll
      for (int n = 0; n < 4; ++n) {
        const long bcol = w * 64 + n * 16 + fr;
        const bf16x8 bHi = *(const bf16x8*)(BTh + bcol * 256 + k0);
        const bf16x8 bLo = *(const bf16x8*)(BTl + bcol * 256 + k0);
        acc[n] = __builtin_amdgcn_mfma_f32_16x16x32_bf16(aHi, bHi, acc[n], 0, 0, 0);
        acc[n] = __builtin_amdgcn_mfma_f32_16x16x32_bf16(aHi, bLo, acc[n], 0, 0, 0);
        acc[n] = __builtin_amdgcn_mfma_f32_16x16x32_bf16(aLo, bHi, acc[n], 0, 0, 0);
      }
    }
    __syncthreads();  // all waves done reading Cur

    if (prod < 7) {
      // write back: C/D layout col = lane&15, row = fg*4 + reg
#pragma unroll
      for (int n = 0; n < 4; ++n)
#pragma unroll
        for (int rr = 0; rr < 4; ++rr) {
          bfpair p = bf_split(acc[n][rr]);
          CurHi[fg * 4 + rr][w * 64 + n * 16 + fr] = p.hi;
          CurLo[fg * 4 + rr][w * 64 + n * 16 + fr] = p.lo;
        }
      __syncthreads();
    } else {
#pragma unroll
      for (int n = 0; n < 4; ++n)
#pragma unroll
        for (int rr = 0; rr < 4; ++rr)
          Qb[(long)(rb + fg * 4 + rr) * 256 + w * 64 + n * 16 + fr] =
              f2bf_rne(acc[n][rr]);
    }
  }
}

// ---------------- Phase 3: GEMM --------------------------------------------
// C[M=65536][256] = A[M][K=256](f32, cvt->bf16) * B[N=256][K=256](bf16, BT)
// Block: BM=128, BN=256, BK=32, 512 thr (8 waves). Wave grid 2x4, 64x64/wave.
// LDS 64KB dbuf; XOR-swizzled staging via pre-swizzled GLOBAL source address.
__launch_bounds__(512)
__global__ void hh_gemm(const float* __restrict__ X,
                        const unsigned short* __restrict__ Qb,
                        float* __restrict__ Y) {
  __shared__ __align__(128) char lds[65536];
  const int tid = threadIdx.x;
  const int lane = tid & 63;
  const int wid = tid >> 6;
  const int wm = wid >> 2;  // 0..1
  const int wn = wid & 3;   // 0..3
  const int fr = lane & 15;
  const int fg = lane >> 4;
  const long bm0 = (long)blockIdx.x * 128;

  auto stage = [&](int buf, int kt) {
#pragma unroll
    for (int r2 = 0; r2 < 2; ++r2) {
      int slot = r2 * 512 + tid;
      int row = slot >> 3, seg = slot & 7;
      int ps = seg ^ (row & 7);
      GLOAD_LDS16(X + (bm0 + row) * 256 + kt * 32 + ps * 4,
                  lds + buf * 16384 + slot * 16);
    }
#pragma unroll
    for (int r2 = 0; r2 < 2; ++r2) {
      int slot = r2 * 512 + tid;
      int row = slot >> 2, seg = slot & 3;
      int ps = seg ^ (row & 3);
      GLOAD_LDS16(Qb + row * 256 + kt * 32 + ps * 8,
                  lds + 32768 + buf * 16384 + slot * 16);
    }
  };

  f32x4 acc[4][4];
#pragma unroll
  for (int m = 0; m < 4; ++m)
#pragma unroll
    for (int n = 0; n < 4; ++n) acc[m][n] = (f32x4){0.f, 0.f, 0.f, 0.f};

  stage(0, 0);
  __syncthreads();

  for (int kt = 0; kt < 8; ++kt) {
    const int cur = kt & 1;
    if (kt < 7) stage(cur ^ 1, kt + 1);

    bf16x8 aF[4], bF[4];
#pragma unroll
    for (int m = 0; m < 4; ++m) {
      int row = wm * 64 + m * 16 + fr;
      int s0 = (2 * fg) ^ (row & 7);
      int s1 = (2 * fg + 1) ^ (row & 7);
      const f32x4 x0 = *(const f32x4*)(lds + cur * 16384 + row * 128 + s0 * 16);
      const f32x4 x1 = *(const f32x4*)(lds + cur * 16384 + row * 128 + s1 * 16);
      bf16x8 t;
      t[0] = (short)f2bf_rne(x0[0]);
      t[1] = (short)f2bf_rne(x0[1]);
      t[2] = (short)f2bf_rne(x0[2]);
      t[3] = (short)f2bf_rne(x0[3]);
      t[4] = (short)f2bf_rne(x1[0]);
      t[5] = (short)f2bf_rne(x1[1]);
      t[6] = (short)f2bf_rne(x1[2]);
      t[7] = (short)f2bf_rne(x1[3]);
      aF[m] = t;
    }
#pragma unroll
    for (int n = 0; n < 4; ++n) {
      int row = wn * 64 + n * 16 + fr;
      int ps = fg ^ (row & 3);
      bF[n] = *(const bf16x8*)(lds + 32768 + cur * 16384 + row * 64 + ps * 16);
    }
#pragma unroll
    for (int m = 0; m < 4; ++m)
#pragma unroll
      for (int n = 0; n < 4; ++n)
        acc[m][n] =
            __builtin_amdgcn_mfma_f32_16x16x32_bf16(aF[m], bF[n], acc[m][n], 0, 0, 0);
    __syncthreads();
  }

#pragma unroll
  for (int m = 0; m < 4; ++m)
#pragma unroll
    for (int n = 0; n < 4; ++n)
#pragma unroll
      for (int r = 0; r < 4; ++r) {
        long grow = bm0 + wm * 64 + m * 16 + fg * 4 + r;
        int gcol = wn * 64 + n * 16 + fr;
        Y[grow * 256 + gcol] = acc[m][n][r];
      }
}

// ---------------------------------------------------------------------------
extern "C" void kernel_launch(void* const* d_in, const int* in_sizes, int n_in,
                              void* d_out, int out_size, void* d_ws, size_t ws_size,
                              hipStream_t stream) {
  const float* x = (const float*)d_in[0];      // [65536][256] f32
  const float* vecs = (const float*)d_in[1];   // [258][256] f32
  float* y = (float*)d_out;                    // [65536][256] f32

  unsigned short* Qb = (unsigned short*)d_ws;  // 256x256 bf16 (128KB)

  // d_out scratch (4MB; every byte written by hh_qchunk before any read;
  // dead before hh_gemm overwrites d_out)
  char* ob = (char*)d_out;
  float* Qc = (float*)(ob);                          // 8 x 64K f32  (2 MB)
  unsigned short* QcTh = (unsigned short*)(ob + 2097152);  // 8 x 64K bf16 (1 MB)
  unsigned short* QcTl = (unsigned short*)(ob + 3145728);  // 8 x 64K bf16 (1 MB)

  hh_qchunk<<<512, 64, 0, stream>>>(vecs, Qc, QcTh, QcTl);
  hh_qmerge<<<16, 256, 0, stream>>>(Qc, QcTh, QcTl, Qb);
  hh_gemm<<<512, 512, 0, stream>>>(x, Qb, y);
}

// Round 22
// 85.127 us; speedup vs baseline: 2.8677x; 1.1530x over previous
//
#include <hip/hip_runtime.h>

// ---------------------------------------------------------------------------
// y = x @ Q^T where Q = H_0 H_1 ... H_{N-1}, H_n = I - 2 v_n v_n^T/(v_n.v_n+eps)
// S=256, N=258, B=65536.
//
// THREE kernels:
//  hh_qchunk: H is SYMMETRIC, so Qc^T = H_last ... H_first (reversed chain).
//             All 8 chunks compute Tc = Qc^T via the R13-proven chain with
//             reversed row order, storing Tc ROW-MAJOR pre-split bf16 hi/lo
//             -- fully coalesced 32B stores (R21's scatter epilogue cost
//             ~18us; this removes it entirely).
//  hh_qmerge: panel chain Cur <- Cur * Qc_i, i=0..7, panel starts at I.
//             B-operand = rows of Tc_i, staged per-kt into LDS via
//             double-buffered global_load_lds (the proven hh_gemm pattern --
//             fire-and-forget, immune to the load-sinking that made R21's
//             register B-loads 56us). 3-term hi/lo MFMA (R12/R21-verified).
//  hh_gemm:   y = x @ Qb^T, bf16 MFMA, BM=128 BN=256 BK=32 (proven, ~10.5us).
//
// d_ws: Qb (128KB). TcH/TcL (1MB each) in d_out scratch (written before
// read every call; dead before hh_gemm overwrites d_out).
// ---------------------------------------------------------------------------

#define GLOAD_LDS16(g, l)                                                      \
  __builtin_amdgcn_global_load_lds(                                            \
      (const __attribute__((address_space(1))) void*)(g),                      \
      (__attribute__((address_space(3))) void*)(l), 16, 0, 0)

typedef __attribute__((ext_vector_type(8))) short bf16x8;
typedef __attribute__((ext_vector_type(4))) float f32x4;

__device__ __forceinline__ unsigned short f2bf_rne(float f) {
  unsigned u = __builtin_bit_cast(unsigned, f);
  return (unsigned short)((u + 0x7fffu + ((u >> 16) & 1u)) >> 16);
}

struct bfpair { unsigned short hi, lo; };

// split fp32 -> hi(bf16) + lo(bf16), x ~= hi + lo, |err| ~ 2^-16 |x|
__device__ __forceinline__ bfpair bf_split(float x) {
  unsigned short hu = f2bf_rne(x);
  float hf = __builtin_bit_cast(float, (unsigned)hu << 16);
  bfpair r;
  r.hi = hu;
  r.lo = f2bf_rne(x - hf);
  return r;
}

// DPP-shuffled add: v + dpp(v). CTRL: 0xB1=quad xor1, 0x4E=quad xor2,
// 0x124=row_ror:4, 0x128=row_ror:8. Pure VALU latency, no LDS.
template <int CTRL>
__device__ __forceinline__ float dpp_add(float v) {
  int t = __builtin_amdgcn_update_dpp(0, __builtin_bit_cast(int, v), CTRL, 0xF,
                                      0xF, true);
  return v + __builtin_bit_cast(float, t);
}

// full 16-lane-group sum (all lanes get the sum)
__device__ __forceinline__ float dpp_sum16(float p) {
  p = dpp_add<0xB1>(p);
  p = dpp_add<0x4E>(p);
  p = dpp_add<0x124>(p);
  p = dpp_add<0x128>(p);
  return p;
}

// ---------------- Phase 1: reversed chunk cascades -> Tc = Qc^T -------------
// 512 blocks x 64 threads (1 wave). Block = (chunk=bx>>6, rowgroup=bx&63).
// Lane l: row-in-group r=l>>4 (4 Tc-rows/block), col-group cl=l&15.
// Chain step m (m=0..32) consumes H row brow+32-m (rows >257 get c=0: no-op).
// Epilogue: Tc row-major bf16 hi/lo, coalesced 32B stores per lane.
__launch_bounds__(64, 1)
__global__ void hh_qchunk(const float* __restrict__ vecs,
                          unsigned short* __restrict__ TcH,
                          unsigned short* __restrict__ TcL) {
  const int l = threadIdx.x;
  const int chunk = blockIdx.x >> 6;   // 0..7
  const int rg = blockIdx.x & 63;      // 0..63
  const int r = l >> 4;                // lane group 0..3
  const int cl = l & 15;               // lane in group
  const int row = rg * 4 + r;
  const int col0 = cl * 16;
  const int brow = chunk * 33;

  __shared__ float cs[36];

  // prologue: cs[m] = c for H row (brow+32-m); m>32 or row>257 -> 0
  for (int m = r; m < 36; m += 4) {
    const int gr = brow + 32 - m;                 // may exceed 257 (chunk 7)
    const int grc = gr > 257 ? 257 : (gr < 0 ? 0 : gr);
    const float4* vp = (const float4*)(vecs + (long)grc * 256 + col0);
    float s = 0.f;
#pragma unroll
    for (int i = 0; i < 4; ++i) {
      float4 t = vp[i];
      s += t.x * t.x + t.y * t.y + t.z * t.z + t.w * t.w;
    }
    s = dpp_sum16(s);
    if (cl == 0) cs[m] = (m < 33 && gr <= 257) ? 2.0f / (s + 1e-16f) : 0.f;
  }
  __syncthreads();

  float q[16];
#pragma unroll
  for (int i = 0; i < 16; ++i) q[i] = (col0 + i == row) ? 1.f : 0.f;

  auto load16 = [&](float(&d)[16], int m) {
    const int gr = brow + 32 - m;
    const int grc = gr > 257 ? 257 : (gr < 0 ? 0 : gr);  // pads: c=0 -> no-op
    const float4* v = (const float4*)(vecs + (long)grc * 256 + col0);
#pragma unroll
    for (int i = 0; i < 4; ++i) {
      float4 t = v[i];
      d[4 * i] = t.x; d[4 * i + 1] = t.y;
      d[4 * i + 2] = t.z; d[4 * i + 3] = t.w;
    }
  };

  auto step = [&](const float(&a)[16], float cc) {
    float p0 = 0.f, p1 = 0.f, p2 = 0.f, p3 = 0.f;
#pragma unroll
    for (int e = 0; e < 4; ++e) {
      p0 = fmaf(q[e], a[e], p0);
      p1 = fmaf(q[4 + e], a[4 + e], p1);
      p2 = fmaf(q[8 + e], a[8 + e], p2);
      p3 = fmaf(q[12 + e], a[12 + e], p3);
    }
    const float p = dpp_sum16((p0 + p1) + (p2 + p3));
    const float s = cc * p;
#pragma unroll
    for (int k = 0; k < 16; ++k) q[k] = fmaf(-s, a[k], q[k]);
  };

  float A0[16], A1[16];
  load16(A0, 0);
  load16(A1, 1);
  float c0 = cs[0], c1 = cs[1];
  for (int m = 0; m < 32; m += 2) {
    const float cn0 = cs[m + 2], cn1 = cs[m + 3];
    step(A0, c0);
    load16(A0, m + 2);
    step(A1, c1);
    load16(A1, m + 3);
    c0 = cn0; c1 = cn1;
  }
  step(A0, c0);  // step 32

  // epilogue: coalesced row-major bf16 hi/lo stores (32B per lane each)
  unsigned short hbuf[16], lbuf[16];
#pragma unroll
  for (int i = 0; i < 16; ++i) {
    bfpair p = bf_split(q[i]);
    hbuf[i] = p.hi;
    lbuf[i] = p.lo;
  }
  const long obase = (long)chunk * 65536 + row * 256 + col0;
#pragma unroll
  for (int i = 0; i < 2; ++i) {
    *(f32x4*)(TcH + obase + 8 * i) = *(const f32x4*)&hbuf[8 * i];
    *(f32x4*)(TcL + obase + 8 * i) = *(const f32x4*)&lbuf[8 * i];
  }
}

// ---------------- Phase 2: chained-panel merge (gload_lds staged B) ---------
// 16 blocks x 256 thr (4 waves). Block owns output rows [16b, 16b+16).
// Panel Cur (16x256) in LDS as bf16 hi/lo (pad 264). Cur starts at I;
// 8 products Cur <- Cur * Qc_i with B-frags from LDS-staged Tc_i k-slices
// (double-buffered global_load_lds, 32KB/slice: hi 16KB + lo 16KB).
__launch_bounds__(256)
__global__ void hh_qmerge(const unsigned short* __restrict__ TcH,
                          const unsigned short* __restrict__ TcL,
                          unsigned short* __restrict__ Qb) {
  __shared__ __align__(128) char Bst[65536];              // 2 bufs x (hi+lo)
  __shared__ __align__(16) unsigned short CurHi[16][264];
  __shared__ __align__(16) unsigned short CurLo[16][264];
  const int tid = threadIdx.x;
  const int lane = tid & 63, w = tid >> 6;   // wave 0..3
  const int fr = lane & 15, fg = lane >> 4;  // frag row / k-group
  const int rb = blockIdx.x * 16;            // block's 16 output rows

  // panel init: identity (bf16 1.0 = 0x3F80 exact)
  {
    const int rr = tid >> 4, c0 = (tid & 15) * 16;
#pragma unroll
    for (int i = 0; i < 16; ++i) {
      CurHi[rr][c0 + i] = (rb + rr == c0 + i) ? 0x3F80 : 0;
      CurLo[rr][c0 + i] = 0;
    }
  }

  // stage Tc_i slice [256 cols][k0..k0+32) -> Bst[buf]: hi then lo.
  // slot = col*4 + seg (16B units); thread t iter j handles slot j*256+t.
  auto stageB = [&](int buf, int prod, int kt) {
    const unsigned short* bh = TcH + (long)prod * 65536 + kt * 32;
    const unsigned short* bl = TcL + (long)prod * 65536 + kt * 32;
    char* dh = Bst + buf * 32768;
    char* dl = Bst + buf * 32768 + 16384;
#pragma unroll
    for (int j = 0; j < 4; ++j) {
      const int slot = j * 256 + tid;
      const int col = slot >> 2, seg = slot & 3;
      GLOAD_LDS16(bh + (long)col * 256 + seg * 8, dh + slot * 16);
    }
#pragma unroll
    for (int j = 0; j < 4; ++j) {
      const int slot = j * 256 + tid;
      const int col = slot >> 2, seg = slot & 3;
      GLOAD_LDS16(bl + (long)col * 256 + seg * 8, dl + slot * 16);
    }
  };

  stageB(0, 0, 0);
  __syncthreads();

  for (int prod = 0; prod < 8; ++prod) {
    f32x4 acc[4];
#pragma unroll
    for (int n = 0; n < 4; ++n) acc[n] = (f32x4){0.f, 0.f, 0.f, 0.f};

    for (int kt = 0; kt < 8; ++kt) {
      const int cur = (prod * 8 + kt) & 1;
      // stage next slice (next kt, or next product's kt=0)
      if (kt < 7)
        stageB(cur ^ 1, prod, kt + 1);
      else if (prod < 7)
        stageB(cur ^ 1, prod + 1, 0);

      const int k0 = kt * 32 + fg * 8;
      const bf16x8 aHi = *(const bf16x8*)&CurHi[fr][k0];
      const bf16x8 aLo = *(const bf16x8*)&CurLo[fr][k0];
#pragma unroll
      for (int n = 0; n < 4; ++n) {
        const int col = w * 64 + n * 16 + fr;
        const bf16x8 bHi = *(const bf16x8*)(Bst + cur * 32768 + col * 64 + fg * 16);
        const bf16x8 bLo =
            *(const bf16x8*)(Bst + cur * 32768 + 16384 + col * 64 + fg * 16);
        acc[n] = __builtin_amdgcn_mfma_f32_16x16x32_bf16(aHi, bHi, acc[n], 0, 0, 0);
        acc[n] = __builtin_amdgcn_mfma_f32_16x16x32_bf16(aHi, bLo, acc[n], 0, 0, 0);
        acc[n] = __builtin_amdgcn_mfma_f32_16x16x32_bf16(aLo, bHi, acc[n], 0, 0, 0);
      }
      __syncthreads();  // staged buffer ready + all reads of cur done
    }

    if (prod < 7) {
      // panel write-back: C/D layout col = lane&15, row = fg*4 + reg
#pragma unroll
      for (int n = 0; n < 4; ++n)
#pragma unroll
        for (int rr = 0; rr < 4; ++rr) {
          bfpair p = bf_split(acc[n][rr]);
          CurHi[fg * 4 + rr][w * 64 + n * 16 + fr] = p.hi;
          CurLo[fg * 4 + rr][w * 64 + n * 16 + fr] = p.lo;
        }
      __syncthreads();
    } else {
#pragma unroll
      for (int n = 0; n < 4; ++n)
#pragma unroll
        for (int rr = 0; rr < 4; ++rr)
          Qb[(long)(rb + fg * 4 + rr) * 256 + w * 64 + n * 16 + fr] =
              f2bf_rne(acc[n][rr]);
    }
  }
}

// ---------------- Phase 3: GEMM --------------------------------------------
// C[M=65536][256] = A[M][K=256](f32, cvt->bf16) * B[N=256][K=256](bf16, BT)
// Block: BM=128, BN=256, BK=32, 512 thr (8 waves). Wave grid 2x4, 64x64/wave.
// LDS 64KB dbuf; XOR-swizzled staging via pre-swizzled GLOBAL source address.
__launch_bounds__(512)
__global__ void hh_gemm(const float* __restrict__ X,
                        const unsigned short* __restrict__ Qb,
                        float* __restrict__ Y) {
  __shared__ __align__(128) char lds[65536];
  const int tid = threadIdx.x;
  const int lane = tid & 63;
  const int wid = tid >> 6;
  const int wm = wid >> 2;  // 0..1
  const int wn = wid & 3;   // 0..3
  const int fr = lane & 15;
  const int fg = lane >> 4;
  const long bm0 = (long)blockIdx.x * 128;

  auto stage = [&](int buf, int kt) {
#pragma unroll
    for (int r2 = 0; r2 < 2; ++r2) {
      int slot = r2 * 512 + tid;
      int row = slot >> 3, seg = slot & 7;
      int ps = seg ^ (row & 7);
      GLOAD_LDS16(X + (bm0 + row) * 256 + kt * 32 + ps * 4,
                  lds + buf * 16384 + slot * 16);
    }
#pragma unroll
    for (int r2 = 0; r2 < 2; ++r2) {
      int slot = r2 * 512 + tid;
      int row = slot >> 2, seg = slot & 3;
      int ps = seg ^ (row & 3);
      GLOAD_LDS16(Qb + row * 256 + kt * 32 + ps * 8,
                  lds + 32768 + buf * 16384 + slot * 16);
    }
  };

  f32x4 acc[4][4];
#pragma unroll
  for (int m = 0; m < 4; ++m)
#pragma unroll
    for (int n = 0; n < 4; ++n) acc[m][n] = (f32x4){0.f, 0.f, 0.f, 0.f};

  stage(0, 0);
  __syncthreads();

  for (int kt = 0; kt < 8; ++kt) {
    const int cur = kt & 1;
    if (kt < 7) stage(cur ^ 1, kt + 1);

    bf16x8 aF[4], bF[4];
#pragma unroll
    for (int m = 0; m < 4; ++m) {
      int row = wm * 64 + m * 16 + fr;
      int s0 = (2 * fg) ^ (row & 7);
      int s1 = (2 * fg + 1) ^ (row & 7);
      const f32x4 x0 = *(const f32x4*)(lds + cur * 16384 + row * 128 + s0 * 16);
      const f32x4 x1 = *(const f32x4*)(lds + cur * 16384 + row * 128 + s1 * 16);
      bf16x8 t;
      t[0] = (short)f2bf_rne(x0[0]);
      t[1] = (short)f2bf_rne(x0[1]);
      t[2] = (short)f2bf_rne(x0[2]);
      t[3] = (short)f2bf_rne(x0[3]);
      t[4] = (short)f2bf_rne(x1[0]);
      t[5] = (short)f2bf_rne(x1[1]);
      t[6] = (short)f2bf_rne(x1[2]);
      t[7] = (short)f2bf_rne(x1[3]);
      aF[m] = t;
    }
#pragma unroll
    for (int n = 0; n < 4; ++n) {
      int row = wn * 64 + n * 16 + fr;
      int ps = fg ^ (row & 3);
      bF[n] = *(const bf16x8*)(lds + 32768 + cur * 16384 + row * 64 + ps * 16);
    }
#pragma unroll
    for (int m = 0; m < 4; ++m)
#pragma unroll
      for (int n = 0; n < 4; ++n)
        acc[m][n] =
            __builtin_amdgcn_mfma_f32_16x16x32_bf16(aF[m], bF[n], acc[m][n], 0, 0, 0);
    __syncthreads();
  }

#pragma unroll
  for (int m = 0; m < 4; ++m)
#pragma unroll
    for (int n = 0; n < 4; ++n)
#pragma unroll
      for (int r = 0; r < 4; ++r) {
        long grow = bm0 + wm * 64 + m * 16 + fg * 4 + r;
        int gcol = wn * 64 + n * 16 + fr;
        Y[grow * 256 + gcol] = acc[m][n][r];
      }
}

// ---------------------------------------------------------------------------
extern "C" void kernel_launch(void* const* d_in, const int* in_sizes, int n_in,
                              void* d_out, int out_size, void* d_ws, size_t ws_size,
                              hipStream_t stream) {
  const float* x = (const float*)d_in[0];      // [65536][256] f32
  const float* vecs = (const float*)d_in[1];   // [258][256] f32
  float* y = (float*)d_out;                    // [65536][256] f32

  unsigned short* Qb = (unsigned short*)d_ws;  // 256x256 bf16 (128KB)

  // d_out scratch (2MB; written by hh_qchunk before any read; dead before
  // hh_gemm overwrites d_out)
  char* ob = (char*)d_out;
  unsigned short* TcH = (unsigned short*)(ob);            // 8 x 64K bf16 (1 MB)
  unsigned short* TcL = (unsigned short*)(ob + 1048576);  // 8 x 64K bf16 (1 MB)

  hh_qchunk<<<512, 64, 0, stream>>>(vecs, TcH, TcL);
  hh_qmerge<<<16, 256, 0, stream>>>(TcH, TcL, Qb);
  hh_gemm<<<512, 512, 0, stream>>>(x, Qb, y);
}